// Round 3
// baseline (1370.871 us; speedup 1.0000x reference)
//
#include <hip/hip_runtime.h>
#include <hip/hip_bf16.h>
#include <math.h>

// Problem constants
#define NTOK  4096      // B*T
#define CDIM  1024
#define HDIM  4096
#define NEXP  8
#define MAXROWS (NTOK * 2 + NEXP * 128)   // 9216 padded slot rows

using short8 = __attribute__((ext_vector_type(8))) short;
using f32x4  = __attribute__((ext_vector_type(4))) float;
using us4    = __attribute__((ext_vector_type(4))) unsigned short;
using us8    = __attribute__((ext_vector_type(8))) unsigned short;

__device__ inline ushort f2bf(float f) {
    uint32_t u = __builtin_bit_cast(uint32_t, f);
    uint32_t r = (u + 0x7FFFu + ((u >> 16) & 1u)) >> 16;
    return (ushort)r;
}

// async global->LDS, 16 B per lane; LDS dest = wave-uniform base + lane*16
__device__ __forceinline__ void gl_lds16(const void* g, void* l) {
    __builtin_amdgcn_global_load_lds(
        (const __attribute__((address_space(1))) void*)(void*)g,
        (__attribute__((address_space(3))) void*)l, 16, 0, 0);
}

// ---------------------------------------------------------------------------
// Gate: one wave per token. fp32 logits, top-2, normalized weights.
__global__ __launch_bounds__(256)
void gate_kernel(const float* __restrict__ x, const float* __restrict__ Wg,
                 const float* __restrict__ bg, int* __restrict__ counts,
                 int4* __restrict__ tchoice, float2* __restrict__ tw) {
    int wave = threadIdx.x >> 6, lane = threadIdx.x & 63;
    int t = blockIdx.x * 4 + wave;
    const float* xr = x + (size_t)t * CDIM;

    float acc[NEXP];
#pragma unroll
    for (int e = 0; e < NEXP; e++) acc[e] = 0.f;

#pragma unroll
    for (int i = 0; i < CDIM / 64; i++) {
        int c = lane + 64 * i;
        float xv = xr[c];
        const float* wr = Wg + (size_t)c * NEXP;
#pragma unroll
        for (int e = 0; e < NEXP; e++) acc[e] += xv * wr[e];
    }
#pragma unroll
    for (int e = 0; e < NEXP; e++) {
        float v = acc[e];
        for (int off = 32; off > 0; off >>= 1) v += __shfl_xor(v, off);
        acc[e] = v + bg[e];
    }
    if (lane == 0) {
        int i1 = 0; float m1 = acc[0];
#pragma unroll
        for (int e = 1; e < NEXP; e++) if (acc[e] > m1) { m1 = acc[e]; i1 = e; }
        int i2 = -1; float m2 = -1e30f;
#pragma unroll
        for (int e = 0; e < NEXP; e++) if (e != i1 && acc[e] > m2) { m2 = acc[e]; i2 = e; }
        float w0 = 1.f / (1.f + expf(m2 - m1));  // softmax top-2 renormalized
        float w1 = 1.f - w0;
        int p0 = atomicAdd(&counts[i1], 1);
        int p1 = atomicAdd(&counts[i2], 1);
        tchoice[t] = make_int4(i1, p0, i2, p1);
        tw[t] = make_float2(w0, w1);
    }
}

// ---------------------------------------------------------------------------
// Exclusive scan of 128-aligned expert region bases (tiny, 1 block)
__global__ void scan_kernel(const int* __restrict__ counts, int* __restrict__ bases) {
    if (threadIdx.x == 0) {
        int b = 0;
        for (int e = 0; e < NEXP; e++) {
            bases[e] = b;
            b += ((counts[e] + 127) >> 7) << 7;
        }
    }
}

// ---------------------------------------------------------------------------
// Pack: one block per token; copy x row (f32->bf16) to both slot rows.
__global__ __launch_bounds__(256)
void pack_kernel(const float* __restrict__ x, const int4* __restrict__ tchoice,
                 const float2* __restrict__ tw, const int* __restrict__ bases,
                 ushort* __restrict__ xpack, float* __restrict__ wpack,
                 int* __restrict__ tokpack) {
    int t = blockIdx.x, tid = threadIdx.x;
    int4 ch = tchoice[t];
    float2 wv = tw[t];
    int d1 = bases[ch.x] + ch.y;
    int d2 = bases[ch.z] + ch.w;
    float4 v = ((const float4*)(x + (size_t)t * CDIM))[tid];
    us4 o;
    o[0] = f2bf(v.x); o[1] = f2bf(v.y); o[2] = f2bf(v.z); o[3] = f2bf(v.w);
    *(us4*)&xpack[(size_t)d1 * CDIM + tid * 4] = o;
    *(us4*)&xpack[(size_t)d2 * CDIM + tid * 4] = o;
    if (tid == 0) {
        wpack[d1] = wv.x; tokpack[d1] = t;
        wpack[d2] = wv.y; tokpack[d2] = t;
    }
}

// ---------------------------------------------------------------------------
// Transpose + fp32->bf16: in [E][R][Cc] f32 -> out [E][Cc][R] bf16
// 64x64 tile; LDS f32 pitch 65 (scalar read/write both <=2-way banks);
// float4 global loads (256 B/16 lanes), us8 16 B global stores.
__global__ __launch_bounds__(256)
void transpose_kernel(const float* __restrict__ in, ushort* __restrict__ out,
                      int R, int Cc) {
    __shared__ float tile[64 * 65];
    int e = blockIdx.z;
    const float* src = in + (size_t)e * R * Cc;
    ushort* dst = out + (size_t)e * Cc * R;
    int c0 = blockIdx.x * 64, r0 = blockIdx.y * 64;
    int tid = threadIdx.x, tx = tid & 15, ty = tid >> 4;
#pragma unroll
    for (int j = 0; j < 4; j++) {
        float4 v = *(const float4*)&src[(size_t)(r0 + ty + 16 * j) * Cc + c0 + tx * 4];
        int base = (ty + 16 * j) * 65 + tx * 4;
        tile[base + 0] = v.x; tile[base + 1] = v.y;
        tile[base + 2] = v.z; tile[base + 3] = v.w;
    }
    __syncthreads();
    int rb = tid & 7, ccb = tid >> 3;   // ccb 0..31
#pragma unroll
    for (int p = 0; p < 2; p++) {
        int cc = ccb + 32 * p;
        us8 o;
#pragma unroll
        for (int i = 0; i < 8; i++) o[i] = f2bf(tile[(rb * 8 + i) * 65 + cc]);
        *(us8*)&dst[(size_t)(c0 + cc) * R + r0 + rb * 8] = o;
    }
}

// ---------------------------------------------------------------------------
// Dense per-expert GEMM on packed rows. 128x128 tile, BK=64, XOR-swizzled LDS,
// global_load_lds width=16. A: bf16 [row][K] at bases[e]; Bt: bf16 [E][N][K].
// GELU=1: out h bf16 rows. ATOMIC=1: split-K=2 (grid.z = e*2+kh), epilogue
// atomicAdd w*(acc [+ bias if kh==0]) into outA[token*CDIM + col].
template<int GELU, int ATOMIC>
__global__ __launch_bounds__(256)
void moe_gemm(const ushort* __restrict__ A, const ushort* __restrict__ Bt,
              const float* __restrict__ bias, const int* __restrict__ counts,
              const int* __restrict__ bases, ushort* __restrict__ outH,
              float* __restrict__ outA, const float* __restrict__ wpack,
              const int* __restrict__ tokpack, int K, int N) {
    int bz = blockIdx.z;
    int e  = ATOMIC ? (bz >> 1) : bz;
    int kh = ATOMIC ? (bz & 1) : 0;
    int kspan = ATOMIC ? (K >> 1) : K;
    int k0 = kh * kspan;

    int cnt = counts[e], base = bases[e];
    int m0 = blockIdx.x * 128;
    if (m0 >= cnt) return;
    int n0 = blockIdx.y * 128;

    const ushort* Ae = A + (size_t)base * K;
    const ushort* Be = Bt + (size_t)e * N * K;

    __shared__ ushort As[128 * 64];
    __shared__ ushort Bs[128 * 64];

    int tid = threadIdx.x, lane = tid & 63, w = tid >> 6;
    int wm = (w >> 1) * 64, wn = (w & 1) * 64;
    int quad = lane >> 4, l16 = lane & 15;
    int rm = l16 & 7;
    int xo0 = ((quad ^ rm) << 3);       // ks=0 col-block byte/2 offset
    // ks=1 offset is xo0 ^ 32 (q -> q^4)

    int srow = tid >> 3;                // 0..31
    int cg   = (tid & 7) ^ (srow & 7);  // global col-block (loop-invariant)

    f32x4 acc[4][4] = {};

    for (int kt = k0; kt < k0 + kspan; kt += 64) {
#pragma unroll
        for (int s = 0; s < 4; s++) {
            int row = s * 32 + srow;
            gl_lds16(Ae + (size_t)(m0 + row) * K + kt + cg * 8, &As[(s * 32 + w * 8) * 64]);
            gl_lds16(Be + (size_t)(n0 + row) * K + kt + cg * 8, &Bs[(s * 32 + w * 8) * 64]);
        }
        __syncthreads();
#pragma unroll
        for (int ks = 0; ks < 2; ks++) {
            int xo = xo0 ^ (ks << 5);
            short8 a[4], b[4];
#pragma unroll
            for (int mt = 0; mt < 4; mt++)
                a[mt] = *(short8*)&As[(wm + mt * 16 + l16) * 64 + xo];
#pragma unroll
            for (int nt = 0; nt < 4; nt++)
                b[nt] = *(short8*)&Bs[(wn + nt * 16 + l16) * 64 + xo];
#pragma unroll
            for (int mt = 0; mt < 4; mt++)
#pragma unroll
                for (int nt = 0; nt < 4; nt++)
                    acc[mt][nt] = __builtin_amdgcn_mfma_f32_16x16x32_bf16(
                        a[mt], b[nt], acc[mt][nt], 0, 0, 0);
        }
        __syncthreads();
    }

    // Epilogue. C/D layout: col = lane&15, row = (lane>>4)*4 + reg.
    const float* be = bias + (size_t)e * N;
#pragma unroll
    for (int mt = 0; mt < 4; mt++) {
#pragma unroll
        for (int r = 0; r < 4; r++) {
            int lrow = wm + mt * 16 + quad * 4 + r;
            if (m0 + lrow < cnt) {
                int prow = base + m0 + lrow;
                if (GELU) {
                    size_t ob = (size_t)prow * N;
#pragma unroll
                    for (int nt = 0; nt < 4; nt++) {
                        int col = n0 + wn + nt * 16 + l16;
                        float val = acc[mt][nt][r] + be[col];
                        val = 0.5f * val * (1.0f + erff(val * 0.70710678118654752f));
                        outH[ob + col] = f2bf(val);
                    }
                } else {
                    float wv = wpack[prow];
                    size_t ob = (size_t)tokpack[prow] * CDIM;
#pragma unroll
                    for (int nt = 0; nt < 4; nt++) {
                        int col = n0 + wn + nt * 16 + l16;
                        float val = acc[mt][nt][r];
                        if (kh == 0) val += be[col];
                        atomicAdd(&outA[ob + col], val * wv);
                    }
                }
            }
        }
    }
}

// ---------------------------------------------------------------------------
extern "C" void kernel_launch(void* const* d_in, const int* in_sizes, int n_in,
                              void* d_out, int out_size, void* d_ws, size_t ws_size,
                              hipStream_t stream) {
    const float* x  = (const float*)d_in[0];
    const float* Wg = (const float*)d_in[1];
    const float* bg = (const float*)d_in[2];
    const float* W1 = (const float*)d_in[3];
    const float* b1 = (const float*)d_in[4];
    const float* W2 = (const float*)d_in[5];
    const float* b2 = (const float*)d_in[6];
    float* out = (float*)d_out;
    char* ws = (char*)d_ws;

    // workspace layout
    size_t off = 0;
    int*    counts  = (int*)(ws + off);    off += 256;
    int*    bases   = (int*)(ws + off);    off += 256;
    int4*   tchoice = (int4*)(ws + off);   off += (size_t)NTOK * 16;               // 64 KB
    float2* tw      = (float2*)(ws + off); off += (size_t)NTOK * 8;                // 32 KB
    float*  wpack   = (float*)(ws + off);  off += (size_t)MAXROWS * 4;             // 36 KB
    int*    tokpack = (int*)(ws + off);    off += (size_t)MAXROWS * 4;             // 36 KB
    off = (off + 255) & ~(size_t)255;
    ushort* xpack   = (ushort*)(ws + off); off += (size_t)MAXROWS * CDIM * 2;      // 18.9 MB
    ushort* WT      = (ushort*)(ws + off); off += (size_t)NEXP * CDIM * HDIM * 2;  // 64 MB (W1T/W2T shared)
    ushort* h       = (ushort*)(ws + off); off += (size_t)MAXROWS * HDIM * 2;      // 75.5 MB

    hipMemsetAsync(counts, 0, 2 * 256, stream);
    hipMemsetAsync(xpack, 0, (size_t)MAXROWS * CDIM * 2, stream);    // zero pad rows
    hipMemsetAsync(out, 0, (size_t)NTOK * CDIM * 4, stream);         // atomic target

    gate_kernel<<<NTOK / 4, 256, 0, stream>>>(x, Wg, bg, counts, tchoice, tw);
    scan_kernel<<<1, 64, 0, stream>>>(counts, bases);
    pack_kernel<<<NTOK, 256, 0, stream>>>(x, tchoice, tw, bases, xpack, wpack, tokpack);

    // W1 [E][C][H] -> WT [E][H][C] bf16
    transpose_kernel<<<dim3(HDIM / 64, CDIM / 64, NEXP), 256, 0, stream>>>(
        W1, WT, CDIM, HDIM);

    // h = gelu(xpack @ W1 + b1), bf16, packed rows
    moe_gemm<1, 0><<<dim3(32, HDIM / 128, NEXP), 256, 0, stream>>>(
        xpack, WT, b1, counts, bases, h, nullptr, nullptr, nullptr, CDIM, HDIM);

    // W2 [E][H][C] -> WT [E][C][H] bf16 (reuses WT; stream-ordered after G1)
    transpose_kernel<<<dim3(CDIM / 64, HDIM / 64, NEXP), 256, 0, stream>>>(
        W2, WT, HDIM, CDIM);

    // out[token] += w * (h @ W2 + b2), split-K=2, atomic epilogue
    moe_gemm<0, 1><<<dim3(32, CDIM / 128, NEXP * 2), 256, 0, stream>>>(
        h, WT, b2, counts, bases, nullptr, out, wpack, tokpack, HDIM, CDIM);
}

// Round 4
// 753.610 us; speedup vs baseline: 1.8191x; 1.8191x over previous
//
#include <hip/hip_runtime.h>
#include <hip/hip_bf16.h>
#include <math.h>

// Problem constants
#define NTOK  4096      // B*T
#define CDIM  1024
#define HDIM  4096
#define NEXP  8
#define MAXROWS (NTOK * 2 + NEXP * 128)   // 9216 padded slot rows
#define MAXTILES 72                       // sum_e ceil(cnt_e/128) <= 64+7 = 71

using short8 = __attribute__((ext_vector_type(8))) short;
using f32x4  = __attribute__((ext_vector_type(4))) float;
using us4    = __attribute__((ext_vector_type(4))) unsigned short;
using us8    = __attribute__((ext_vector_type(8))) unsigned short;

__device__ inline ushort f2bf(float f) {
    uint32_t u = __builtin_bit_cast(uint32_t, f);
    uint32_t r = (u + 0x7FFFu + ((u >> 16) & 1u)) >> 16;
    return (ushort)r;
}

// async global->LDS, 16 B per lane; LDS dest = wave-uniform base + lane*16
__device__ __forceinline__ void gl_lds16(const void* g, void* l) {
    __builtin_amdgcn_global_load_lds(
        (const __attribute__((address_space(1))) void*)(void*)g,
        (__attribute__((address_space(3))) void*)l, 16, 0, 0);
}

// ---------------------------------------------------------------------------
// Gate: one wave per token. fp32 logits, top-2, normalized weights.
__global__ __launch_bounds__(256)
void gate_kernel(const float* __restrict__ x, const float* __restrict__ Wg,
                 const float* __restrict__ bg, int* __restrict__ counts,
                 int4* __restrict__ tchoice, float2* __restrict__ tw) {
    int wave = threadIdx.x >> 6, lane = threadIdx.x & 63;
    int t = blockIdx.x * 4 + wave;
    const float* xr = x + (size_t)t * CDIM;

    float acc[NEXP];
#pragma unroll
    for (int e = 0; e < NEXP; e++) acc[e] = 0.f;

#pragma unroll
    for (int i = 0; i < CDIM / 64; i++) {
        int c = lane + 64 * i;
        float xv = xr[c];
        const float4* wr = (const float4*)(Wg + (size_t)c * NEXP);
        float4 w0 = wr[0], w1 = wr[1];
        acc[0] += xv * w0.x; acc[1] += xv * w0.y;
        acc[2] += xv * w0.z; acc[3] += xv * w0.w;
        acc[4] += xv * w1.x; acc[5] += xv * w1.y;
        acc[6] += xv * w1.z; acc[7] += xv * w1.w;
    }
#pragma unroll
    for (int e = 0; e < NEXP; e++) {
        float v = acc[e];
        for (int off = 32; off > 0; off >>= 1) v += __shfl_xor(v, off);
        acc[e] = v + bg[e];
    }
    if (lane == 0) {
        int i1 = 0; float m1 = acc[0];
#pragma unroll
        for (int e = 1; e < NEXP; e++) if (acc[e] > m1) { m1 = acc[e]; i1 = e; }
        int i2 = -1; float m2 = -1e30f;
#pragma unroll
        for (int e = 0; e < NEXP; e++) if (e != i1 && acc[e] > m2) { m2 = acc[e]; i2 = e; }
        float w0 = 1.f / (1.f + expf(m2 - m1));  // softmax top-2 renormalized
        float w1 = 1.f - w0;
        int p0 = atomicAdd(&counts[i1], 1);
        int p1 = atomicAdd(&counts[i2], 1);
        tchoice[t] = make_int4(i1, p0, i2, p1);
        tw[t] = make_float2(w0, w1);
    }
}

// ---------------------------------------------------------------------------
// Scan: 128-aligned expert bases + (expert, m-tile) work list.
__global__ void scan_kernel(const int* __restrict__ counts, int* __restrict__ bases,
                            int* __restrict__ tmeta) {
    if (threadIdx.x == 0) {
        int b = 0, nt = 0;
        for (int e = 0; e < NEXP; e++) {
            bases[e] = b;
            int tiles = (counts[e] + 127) >> 7;
            for (int m = 0; m < tiles; m++) tmeta[1 + nt++] = (e << 16) | m;
            b += tiles << 7;
        }
        tmeta[0] = nt;
    }
}

// ---------------------------------------------------------------------------
// Pack: one block per token; copy x row (f32->bf16) to both slot rows.
// Pad rows are NOT zeroed: they contain finite poison, feed only into
// accumulator rows that the GEMM epilogues never store (guarded by cnt).
__global__ __launch_bounds__(256)
void pack_kernel(const float* __restrict__ x, const int4* __restrict__ tchoice,
                 const float2* __restrict__ tw, const int* __restrict__ bases,
                 ushort* __restrict__ xpack, float* __restrict__ wpack,
                 int* __restrict__ tokpack) {
    int t = blockIdx.x, tid = threadIdx.x;
    int4 ch = tchoice[t];
    float2 wv = tw[t];
    int d1 = bases[ch.x] + ch.y;
    int d2 = bases[ch.z] + ch.w;
    float4 v = ((const float4*)(x + (size_t)t * CDIM))[tid];
    us4 o;
    o[0] = f2bf(v.x); o[1] = f2bf(v.y); o[2] = f2bf(v.z); o[3] = f2bf(v.w);
    *(us4*)&xpack[(size_t)d1 * CDIM + tid * 4] = o;
    *(us4*)&xpack[(size_t)d2 * CDIM + tid * 4] = o;
    if (tid == 0) {
        wpack[d1] = wv.x; tokpack[d1] = t;
        wpack[d2] = wv.y; tokpack[d2] = t;
    }
}

// ---------------------------------------------------------------------------
// Transpose + fp32->bf16: in [E][R][Cc] f32 -> out [E][Cc][R] bf16
// 64x64 tile; LDS f32 pitch 65 (max 2-way banks both phases);
// float4 global loads, us8 16 B global stores.
__global__ __launch_bounds__(256)
void transpose_kernel(const float* __restrict__ in, ushort* __restrict__ out,
                      int R, int Cc) {
    __shared__ float tile[64 * 65];
    int e = blockIdx.z;
    const float* src = in + (size_t)e * R * Cc;
    ushort* dst = out + (size_t)e * Cc * R;
    int c0 = blockIdx.x * 64, r0 = blockIdx.y * 64;
    int tid = threadIdx.x, tx = tid & 15, ty = tid >> 4;
#pragma unroll
    for (int j = 0; j < 4; j++) {
        float4 v = *(const float4*)&src[(size_t)(r0 + ty + 16 * j) * Cc + c0 + tx * 4];
        int base = (ty + 16 * j) * 65 + tx * 4;
        tile[base + 0] = v.x; tile[base + 1] = v.y;
        tile[base + 2] = v.z; tile[base + 3] = v.w;
    }
    __syncthreads();
    int rb = tid & 7, ccb = tid >> 3;   // ccb 0..31
#pragma unroll
    for (int p = 0; p < 2; p++) {
        int cc = ccb + 32 * p;
        us8 o;
#pragma unroll
        for (int i = 0; i < 8; i++) o[i] = f2bf(tile[(rb * 8 + i) * 65 + cc]);
        *(us8*)&dst[(size_t)(c0 + cc) * R + r0 + rb * 8] = o;
    }
}

// ---------------------------------------------------------------------------
// Dense per-expert GEMM on packed rows — m97-proven core (BK=32, pitch-32
// LDS, linear staging, global_load_lds width=16). Work list picks (e, m0).
// grid: x = n-tiles (fastest, A-tile L2 reuse), y = work-list tile, z = split-K.
// GELU=1: h bf16 rows out.  ATOMIC=1: atomicAdd w*(acc[+bias if z==0]) into out.
template<int GELU, int ATOMIC>
__global__ __launch_bounds__(256)
void moe_gemm(const ushort* __restrict__ A, const ushort* __restrict__ Bt,
              const float* __restrict__ bias, const int* __restrict__ tmeta,
              const int* __restrict__ counts, const int* __restrict__ bases,
              ushort* __restrict__ outH, float* __restrict__ outA,
              const float* __restrict__ wpack, const int* __restrict__ tokpack,
              int K, int N) {
    int ti = blockIdx.y;
    if (ti >= tmeta[0]) return;
    int packed = tmeta[1 + ti];
    int e  = packed >> 16;
    int m0 = (packed & 0xffff) << 7;
    int n0 = blockIdx.x * 128;
    int kspan = K / gridDim.z;
    int k0 = blockIdx.z * kspan;
    int cnt = counts[e], base = bases[e];

    const ushort* Ae = A + (size_t)base * K;
    const ushort* Be = Bt + (size_t)e * N * K;

    __shared__ ushort As[128 * 32];
    __shared__ ushort Bs[128 * 32];

    int tid = threadIdx.x, lane = tid & 63, w = tid >> 6;
    int wm = (w >> 1) * 64, wn = (w & 1) * 64;
    int quad = lane >> 4, l16 = lane & 15;
    int srow = tid >> 2;            // 0..63 ; wave w covers rows [w*16, w*16+16)
    int scol = (tid & 3) * 8;       // bf16 elem offset {0,8,16,24}

    f32x4 acc[4][4] = {};

    for (int kt = k0; kt < k0 + kspan; kt += 32) {
#pragma unroll
        for (int s = 0; s < 2; s++) {
            int row = srow + s * 64;
            gl_lds16(Ae + (size_t)(m0 + row) * K + kt + scol, &As[(w * 16 + s * 64) * 32]);
            gl_lds16(Be + (size_t)(n0 + row) * K + kt + scol, &Bs[(w * 16 + s * 64) * 32]);
        }
        __syncthreads();

        short8 a[4], b[4];
#pragma unroll
        for (int mt = 0; mt < 4; mt++)
            a[mt] = *(short8*)&As[(wm + mt * 16 + l16) * 32 + quad * 8];
#pragma unroll
        for (int nt = 0; nt < 4; nt++)
            b[nt] = *(short8*)&Bs[(wn + nt * 16 + l16) * 32 + quad * 8];
#pragma unroll
        for (int mt = 0; mt < 4; mt++)
#pragma unroll
            for (int nt = 0; nt < 4; nt++)
                acc[mt][nt] = __builtin_amdgcn_mfma_f32_16x16x32_bf16(
                    a[mt], b[nt], acc[mt][nt], 0, 0, 0);
        __syncthreads();
    }

    // Epilogue. C/D layout: col = lane&15, row = (lane>>4)*4 + reg.
    const float* be = bias + (size_t)e * N;
#pragma unroll
    for (int mt = 0; mt < 4; mt++) {
#pragma unroll
        for (int r = 0; r < 4; r++) {
            int lrow = wm + mt * 16 + quad * 4 + r;
            if (m0 + lrow < cnt) {
                int prow = base + m0 + lrow;
                if (GELU) {
                    size_t ob = (size_t)prow * N;
#pragma unroll
                    for (int nt = 0; nt < 4; nt++) {
                        int col = n0 + wn + nt * 16 + l16;
                        float val = acc[mt][nt][r] + be[col];
                        val = 0.5f * val * (1.0f + erff(val * 0.70710678118654752f));
                        outH[ob + col] = f2bf(val);
                    }
                }
                if (ATOMIC) {
                    float wv = wpack[prow];
                    size_t ob = (size_t)tokpack[prow] * CDIM;
#pragma unroll
                    for (int nt = 0; nt < 4; nt++) {
                        int col = n0 + wn + nt * 16 + l16;
                        float val = acc[mt][nt][r];
                        if (blockIdx.z == 0) val += be[col];
                        atomicAdd(&outA[ob + col], val * wv);
                    }
                }
            }
        }
    }
}

// ---------------------------------------------------------------------------
extern "C" void kernel_launch(void* const* d_in, const int* in_sizes, int n_in,
                              void* d_out, int out_size, void* d_ws, size_t ws_size,
                              hipStream_t stream) {
    const float* x  = (const float*)d_in[0];
    const float* Wg = (const float*)d_in[1];
    const float* bg = (const float*)d_in[2];
    const float* W1 = (const float*)d_in[3];
    const float* b1 = (const float*)d_in[4];
    const float* W2 = (const float*)d_in[5];
    const float* b2 = (const float*)d_in[6];
    float* out = (float*)d_out;
    char* ws = (char*)d_ws;

    // workspace layout
    size_t off = 0;
    int*    counts  = (int*)(ws + off);    off += 256;
    int*    bases   = (int*)(ws + off);    off += 256;
    int*    tmeta   = (int*)(ws + off);    off += 512;                             // 1+72 ints
    int4*   tchoice = (int4*)(ws + off);   off += (size_t)NTOK * 16;               // 64 KB
    float2* tw      = (float2*)(ws + off); off += (size_t)NTOK * 8;                // 32 KB
    float*  wpack   = (float*)(ws + off);  off += (size_t)MAXROWS * 4;             // 36 KB
    int*    tokpack = (int*)(ws + off);    off += (size_t)MAXROWS * 4;             // 36 KB
    off = (off + 255) & ~(size_t)255;
    ushort* xpack   = (ushort*)(ws + off); off += (size_t)MAXROWS * CDIM * 2;      // 18.9 MB
    ushort* WT      = (ushort*)(ws + off); off += (size_t)NEXP * CDIM * HDIM * 2;  // 64 MB (W1T/W2T shared)
    ushort* h       = (ushort*)(ws + off); off += (size_t)MAXROWS * HDIM * 2;      // 75.5 MB

    hipMemsetAsync(counts, 0, 256, stream);
    hipMemsetAsync(out, 0, (size_t)NTOK * CDIM * 4, stream);   // atomic target

    gate_kernel<<<NTOK / 4, 256, 0, stream>>>(x, Wg, bg, counts, tchoice, tw);
    scan_kernel<<<1, 64, 0, stream>>>(counts, bases, tmeta);
    pack_kernel<<<NTOK, 256, 0, stream>>>(x, tchoice, tw, bases, xpack, wpack, tokpack);

    // W1 [E][C][H] -> WT [E][H][C] bf16
    transpose_kernel<<<dim3(HDIM / 64, CDIM / 64, NEXP), 256, 0, stream>>>(
        W1, WT, CDIM, HDIM);

    // h = gelu(xpack @ W1 + b1), bf16, packed rows
    moe_gemm<1, 0><<<dim3(HDIM / 128, MAXTILES, 1), 256, 0, stream>>>(
        xpack, WT, b1, tmeta, counts, bases, h, nullptr, nullptr, nullptr,
        CDIM, HDIM);

    // W2 [E][H][C] -> WT [E][C][H] bf16 (reuses WT; stream-ordered after G1)
    transpose_kernel<<<dim3(CDIM / 64, HDIM / 64, NEXP), 256, 0, stream>>>(
        W2, WT, HDIM, CDIM);

    // out[token] += w * (h @ W2 + b2), split-K=2, atomic epilogue
    moe_gemm<0, 1><<<dim3(CDIM / 128, MAXTILES, 2), 256, 0, stream>>>(
        h, WT, b2, tmeta, counts, bases, nullptr, out, wpack, tokpack,
        HDIM, CDIM);
}

// Round 5
// 711.503 us; speedup vs baseline: 1.9267x; 1.0592x over previous
//
#include <hip/hip_runtime.h>
#include <hip/hip_bf16.h>
#include <math.h>

// Problem constants
#define NTOK  4096      // B*T
#define CDIM  1024
#define HDIM  4096
#define NEXP  8
#define NSLOT (NTOK * 2)
#define MAXTILES 72     // sum_e ceil(cnt_e/128) <= 64 + 7 = 71

using short8 = __attribute__((ext_vector_type(8))) short;
using f32x4  = __attribute__((ext_vector_type(4))) float;
using us4    = __attribute__((ext_vector_type(4))) unsigned short;
using us8    = __attribute__((ext_vector_type(8))) unsigned short;

__device__ inline ushort f2bf(float f) {
    uint32_t u = __builtin_bit_cast(uint32_t, f);
    uint32_t r = (u + 0x7FFFu + ((u >> 16) & 1u)) >> 16;
    return (ushort)r;
}

// async global->LDS, 16 B per lane; LDS dest = wave-uniform base + lane*16
__device__ __forceinline__ void gl_lds16(const void* g, void* l) {
    __builtin_amdgcn_global_load_lds(
        (const __attribute__((address_space(1))) void*)(void*)g,
        (__attribute__((address_space(3))) void*)l, 16, 0, 0);
}

// ---------------------------------------------------------------------------
// Gate: 16 tokens/block, Wg staged once into LDS (transposed [e][c] so the
// FMA reads are conflict-free). Emits tlist slots + weights + xbf conversion.
__global__ __launch_bounds__(256)
void gate_kernel(const float* __restrict__ x, const float* __restrict__ Wg,
                 const float* __restrict__ bg, int* __restrict__ counts,
                 int* __restrict__ tlist, float* __restrict__ wslot,
                 ushort* __restrict__ xbf) {
    __shared__ float wgs[NEXP * CDIM];   // 32 KB
    int tid = threadIdx.x;
    // stage Wg[c][e] -> wgs[e*CDIM + c]; global reads fully coalesced
#pragma unroll
    for (int i = 0; i < CDIM; i += 32) {
        int c = i + (tid >> 3), e = tid & 7;
        wgs[e * CDIM + c] = Wg[c * NEXP + e];
    }
    __syncthreads();

    int wave = tid >> 6, lane = tid & 63;
#pragma unroll
    for (int j = 0; j < 4; j++) {
        int t = blockIdx.x * 16 + wave * 4 + j;
        const float* xr = x + (size_t)t * CDIM;
        float acc[NEXP];
#pragma unroll
        for (int e = 0; e < NEXP; e++) acc[e] = 0.f;
#pragma unroll
        for (int i = 0; i < CDIM / 64; i++) {
            int c = lane + 64 * i;
            float xv = xr[c];
            xbf[(size_t)t * CDIM + c] = f2bf(xv);
#pragma unroll
            for (int e = 0; e < NEXP; e++) acc[e] += xv * wgs[e * CDIM + c];
        }
#pragma unroll
        for (int e = 0; e < NEXP; e++) {
            float v = acc[e];
            for (int off = 32; off > 0; off >>= 1) v += __shfl_xor(v, off);
            acc[e] = v + bg[e];
        }
        if (lane == 0) {
            int i1 = 0; float m1 = acc[0];
#pragma unroll
            for (int e = 1; e < NEXP; e++) if (acc[e] > m1) { m1 = acc[e]; i1 = e; }
            int i2 = -1; float m2 = -1e30f;
#pragma unroll
            for (int e = 0; e < NEXP; e++) if (e != i1 && acc[e] > m2) { m2 = acc[e]; i2 = e; }
            float w0 = 1.f / (1.f + expf(m2 - m1));  // softmax top-2 renormalized
            float w1 = 1.f - w0;
            int p0 = atomicAdd(&counts[i1], 1);
            tlist[i1 * NTOK + p0] = t * 2;
            int p1 = atomicAdd(&counts[i2], 1);
            tlist[i2 * NTOK + p1] = t * 2 + 1;
            wslot[t * 2]     = w0;
            wslot[t * 2 + 1] = w1;
        }
    }
}

// ---------------------------------------------------------------------------
// Build (expert, m-tile) work list.
__global__ void scan_kernel(const int* __restrict__ counts, int* __restrict__ tmeta) {
    if (threadIdx.x == 0) {
        int nt = 0;
        for (int e = 0; e < NEXP; e++) {
            int tiles = (counts[e] + 127) >> 7;
            for (int m = 0; m < tiles; m++) tmeta[1 + nt++] = (e << 16) | m;
        }
        tmeta[0] = nt;
    }
}

// ---------------------------------------------------------------------------
// Transpose + fp32->bf16: in [E][R][Cc] f32 -> out [E][Cc][R] bf16
// 64x64 tile; LDS f32 pitch 65 (max 2-way banks both phases);
// float4 global loads, us8 16 B global stores. Two named wrappers for rocprof.
__device__ __forceinline__
void transpose_body(const float* __restrict__ in, ushort* __restrict__ out,
                    int R, int Cc) {
    __shared__ float tile[64 * 65];
    int e = blockIdx.z;
    const float* src = in + (size_t)e * R * Cc;
    ushort* dst = out + (size_t)e * Cc * R;
    int c0 = blockIdx.x * 64, r0 = blockIdx.y * 64;
    int tid = threadIdx.x, tx = tid & 15, ty = tid >> 4;
#pragma unroll
    for (int j = 0; j < 4; j++) {
        float4 v = *(const float4*)&src[(size_t)(r0 + ty + 16 * j) * Cc + c0 + tx * 4];
        int base = (ty + 16 * j) * 65 + tx * 4;
        tile[base + 0] = v.x; tile[base + 1] = v.y;
        tile[base + 2] = v.z; tile[base + 3] = v.w;
    }
    __syncthreads();
    int rb = tid & 7, ccb = tid >> 3;   // ccb 0..31
#pragma unroll
    for (int p = 0; p < 2; p++) {
        int cc = ccb + 32 * p;
        us8 o;
#pragma unroll
        for (int i = 0; i < 8; i++) o[i] = f2bf(tile[(rb * 8 + i) * 65 + cc]);
        *(us8*)&dst[(size_t)(c0 + cc) * R + r0 + rb * 8] = o;
    }
}
__global__ __launch_bounds__(256)
void tr_w1_kernel(const float* __restrict__ in, ushort* __restrict__ out) {
    transpose_body(in, out, CDIM, HDIM);
}
__global__ __launch_bounds__(256)
void tr_w2_kernel(const float* __restrict__ in, ushort* __restrict__ out) {
    transpose_body(in, out, HDIM, CDIM);
}

// ---------------------------------------------------------------------------
// Gather-GEMM core (round-2 measured-best m97 structure: BK=32, pitch-32 LDS,
// linear staging, global_load_lds width=16). Work list picks (e, m0).
// MODE 0 (gemm1): A row = rowv>>1 (xbf), out h[rowv] = gelu(acc + b1), bf16.
// MODE 1 (gemm2): A row = rowv (h), atomicAdd wslot[rowv]*(acc + b2) into
//                 out[(rowv>>1)*CDIM + col].
template<int MODE>
__device__ __forceinline__
void gemm_core(const ushort* __restrict__ A, const ushort* __restrict__ Bt,
               const float* __restrict__ bias, const int* __restrict__ tmeta,
               const int* __restrict__ tlist, const int* __restrict__ counts,
               ushort* __restrict__ outH, float* __restrict__ outA,
               const float* __restrict__ wslot, int K, int N) {
    int ti = blockIdx.y;
    if (ti >= tmeta[0]) return;
    int packed = tmeta[1 + ti];
    int e  = packed >> 16;
    int m0 = (packed & 0xffff) << 7;
    int n0 = blockIdx.x * 128;
    int cnt = counts[e];

    __shared__ ushort As[128 * 32];
    __shared__ ushort Bs[128 * 32];
    __shared__ int rowv[128];

    int tid = threadIdx.x;
    if (tid < 128) {
        int r = m0 + tid;
        rowv[tid] = tlist[e * NTOK + (r < cnt ? r : cnt - 1)];
    }
    __syncthreads();

    const ushort* Be = Bt + (size_t)e * N * K;

    f32x4 acc[4][4] = {};

    int lane = tid & 63, w = tid >> 6;
    int wm = (w >> 1) * 64, wn = (w & 1) * 64;
    int quad = lane >> 4, l16 = lane & 15;
    int srow = tid >> 2;            // 0..63 ; wave w covers rows [w*16, w*16+16)
    int scol = (tid & 3) * 8;       // bf16 elem offset {0,8,16,24}

    for (int kt = 0; kt < K; kt += 32) {
#pragma unroll
        for (int s = 0; s < 2; s++) {
            int row = srow + s * 64;
            int arow = MODE == 0 ? (rowv[row] >> 1) : rowv[row];
            gl_lds16(A + (size_t)arow * K + kt + scol, &As[(w * 16 + s * 64) * 32]);
            gl_lds16(Be + (size_t)(n0 + row) * K + kt + scol, &Bs[(w * 16 + s * 64) * 32]);
        }
        __syncthreads();

        short8 a[4], b[4];
#pragma unroll
        for (int mt = 0; mt < 4; mt++)
            a[mt] = *(short8*)&As[(wm + mt * 16 + l16) * 32 + quad * 8];
#pragma unroll
        for (int nt = 0; nt < 4; nt++)
            b[nt] = *(short8*)&Bs[(wn + nt * 16 + l16) * 32 + quad * 8];
#pragma unroll
        for (int mt = 0; mt < 4; mt++)
#pragma unroll
            for (int nt = 0; nt < 4; nt++)
                acc[mt][nt] = __builtin_amdgcn_mfma_f32_16x16x32_bf16(
                    a[mt], b[nt], acc[mt][nt], 0, 0, 0);
        __syncthreads();
    }

    // Epilogue. C/D layout: col = lane&15, row = (lane>>4)*4 + reg.
    const float* be = bias + (size_t)e * N;
#pragma unroll
    for (int mt = 0; mt < 4; mt++) {
#pragma unroll
        for (int r = 0; r < 4; r++) {
            int lrow = wm + mt * 16 + quad * 4 + r;
            if (m0 + lrow < cnt) {
                int v = rowv[lrow];
                if (MODE == 0) {
                    size_t ob = (size_t)v * N;
#pragma unroll
                    for (int nt = 0; nt < 4; nt++) {
                        int col = n0 + wn + nt * 16 + l16;
                        float val = acc[mt][nt][r] + be[col];
                        val = 0.5f * val * (1.0f + erff(val * 0.70710678118654752f));
                        outH[ob + col] = f2bf(val);
                    }
                } else {
                    float wv = wslot[v];
                    size_t ob = (size_t)(v >> 1) * CDIM;
#pragma unroll
                    for (int nt = 0; nt < 4; nt++) {
                        int col = n0 + wn + nt * 16 + l16;
                        atomicAdd(&outA[ob + col], (acc[mt][nt][r] + be[col]) * wv);
                    }
                }
            }
        }
    }
}

__global__ __launch_bounds__(256)
void gemm1_kernel(const ushort* __restrict__ A, const ushort* __restrict__ Bt,
                  const float* __restrict__ bias, const int* __restrict__ tmeta,
                  const int* __restrict__ tlist, const int* __restrict__ counts,
                  ushort* __restrict__ outH) {
    gemm_core<0>(A, Bt, bias, tmeta, tlist, counts, outH, nullptr, nullptr,
                 CDIM, HDIM);
}
__global__ __launch_bounds__(256)
void gemm2_kernel(const ushort* __restrict__ A, const ushort* __restrict__ Bt,
                  const float* __restrict__ bias, const int* __restrict__ tmeta,
                  const int* __restrict__ tlist, const int* __restrict__ counts,
                  float* __restrict__ outA, const float* __restrict__ wslot) {
    gemm_core<1>(A, Bt, bias, tmeta, tlist, counts, nullptr, outA, wslot,
                 HDIM, CDIM);
}

// ---------------------------------------------------------------------------
extern "C" void kernel_launch(void* const* d_in, const int* in_sizes, int n_in,
                              void* d_out, int out_size, void* d_ws, size_t ws_size,
                              hipStream_t stream) {
    const float* x  = (const float*)d_in[0];
    const float* Wg = (const float*)d_in[1];
    const float* bg = (const float*)d_in[2];
    const float* W1 = (const float*)d_in[3];
    const float* b1 = (const float*)d_in[4];
    const float* W2 = (const float*)d_in[5];
    const float* b2 = (const float*)d_in[6];
    float* out = (float*)d_out;
    char* ws = (char*)d_ws;

    // workspace layout
    size_t off = 0;
    int*    counts = (int*)(ws + off);    off += 256;
    int*    tmeta  = (int*)(ws + off);    off += 512;                             // 1+72 ints
    int*    tlist  = (int*)(ws + off);    off += (size_t)NEXP * NTOK * 4;         // 128 KB
    float*  wslot  = (float*)(ws + off);  off += (size_t)NSLOT * 4;               // 32 KB
    off = (off + 255) & ~(size_t)255;
    ushort* xbf    = (ushort*)(ws + off); off += (size_t)NTOK * CDIM * 2;         // 8 MB
    ushort* WT     = (ushort*)(ws + off); off += (size_t)NEXP * CDIM * HDIM * 2;  // 64 MB (W1T/W2T shared)
    ushort* h      = (ushort*)(ws + off); off += (size_t)NSLOT * HDIM * 2;        // 64 MB

    hipMemsetAsync(counts, 0, 256, stream);
    hipMemsetAsync(out, 0, (size_t)NTOK * CDIM * 4, stream);   // atomic target

    gate_kernel<<<NTOK / 16, 256, 0, stream>>>(x, Wg, bg, counts, tlist, wslot, xbf);
    scan_kernel<<<1, 64, 0, stream>>>(counts, tmeta);

    // W1 [E][C][H] -> WT [E][H][C] bf16
    tr_w1_kernel<<<dim3(HDIM / 64, CDIM / 64, NEXP), 256, 0, stream>>>(W1, WT);

    // h[slot] = gelu(x @ W1 + b1), bf16, gathered rows
    gemm1_kernel<<<dim3(HDIM / 128, MAXTILES, 1), 256, 0, stream>>>(
        xbf, WT, b1, tmeta, tlist, counts, h);

    // W2 [E][H][C] -> WT [E][C][H] bf16 (reuses WT; stream-ordered after G1)
    tr_w2_kernel<<<dim3(CDIM / 64, HDIM / 64, NEXP), 256, 0, stream>>>(W2, WT);

    // out[token] += w * (h @ W2 + b2), atomic fused epilogue
    gemm2_kernel<<<dim3(CDIM / 128, MAXTILES, 1), 256, 0, stream>>>(
        h, WT, b2, tmeta, tlist, counts, out, wslot);
}